// Round 3
// baseline (52.446 us; speedup 1.0000x reference)
//
#include <hip/hip_runtime.h>
#include <hip/hip_bf16.h>

#define NN 96
#define DD 64
#define HH 256
#define H2 128

// ---------------- Kernel A: projections ----------------
// grid (96, 5): block.y selects output matrix (pi,pj,ta,tb,tcT).
// 480 blocks -> 5x the latency-hiding parallelism of the fused version;
// each block streams only 64 KB of weights.
__global__ __launch_bounds__(256) void proj_kernel(
    const float* __restrict__ X, const float* __restrict__ W1, const float* __restrict__ b1,
    const float* __restrict__ V1, const float* __restrict__ c1,
    float* __restrict__ pi, float* __restrict__ pj,
    float* __restrict__ ta, float* __restrict__ tb, float* __restrict__ tcT)
{
    const int i = blockIdx.x;
    const int m = blockIdx.y;           // 0..4
    const int h = threadIdx.x;          // 0..255
    __shared__ float xs[DD];
    if (h < DD) xs[h] = X[i*DD + h];
    __syncthreads();

    const float* __restrict__ W =
        (m == 0) ? W1 :
        (m == 1) ? W1 + DD*HH :
        (m == 2) ? V1 :
        (m == 3) ? V1 + DD*HH : V1 + 2*DD*HH;

    float acc = 0.f;
    #pragma unroll 16
    for (int d = 0; d < DD; ++d)
        acc = fmaf(xs[d], W[d*HH + h], acc);

    if      (m == 0) pi[i*HH + h] = acc + b1[h];
    else if (m == 1) pj[i*HH + h] = acc;
    else if (m == 2) ta[i*HH + h] = acc + c1[h];
    else if (m == 3) tb[i*HH + h] = acc;
    else             tcT[h*NN + i] = acc;
}

// ---------------- Kernel B: causal [96,96] ----------------
// grid (96,8): 12 j per block. 256 threads: c2 = t&63 (channel pair c2,c2+64),
// qt = t>>6 (h-quarter, one per wave). W2 software-pipelined through a
// double-buffered 8-q register chunk: 16 coalesced L2 loads issued one full
// chunk (384 FMA ~ 768 cy) ahead of use -> L2 latency fully covered.
__global__ __launch_bounds__(256) void causal_kernel(
    const float* __restrict__ pi, const float* __restrict__ pj,
    const float* __restrict__ W2, const float* __restrict__ b2,
    const float* __restrict__ W3, const float* __restrict__ b3,
    float* __restrict__ out)
{
    const int i  = blockIdx.x;
    const int j0 = blockIdx.y * 12;
    const int t  = threadIdx.x;         // 0..255
    const int c2 = t & 63;
    const int qt = t >> 6;              // 0..3

    __shared__ float smem[4*64*2*12];   // 24 KB; staging then partials
    __shared__ float red[2][12];
    float (*hb)[12]          = (float(*)[12])smem;          // [256][12]
    float (*part)[64][2][12] = (float(*)[64][2][12])smem;   // [4][64][2][12]

    // ---- stage hbT[h][jj] = relu(pi[i][h] + pj[j][h]), h = t ----
    {
        const float p_i = pi[i*HH + t];
        #pragma unroll
        for (int jj = 0; jj < 12; ++jj)
            hb[t][jj] = fmaxf(p_i + pj[(j0 + jj)*HH + t], 0.f);
    }
    __syncthreads();

    float acc0[12], acc1[12];
    #pragma unroll
    for (int jj = 0; jj < 12; ++jj) { acc0[jj] = 0.f; acc1[jj] = 0.f; }

    const float* __restrict__ w2p = W2 + (qt*64)*H2 + c2;

    float wa[8], wb[8];
    #pragma unroll
    for (int u = 0; u < 8; ++u) { wa[u] = w2p[u*H2]; wb[u] = w2p[u*H2 + 64]; }

    #pragma unroll
    for (int cch = 0; cch < 8; ++cch) {
        // prefetch next chunk (wraps to 0 on last iter; values unused)
        float xa[8], xb[8];
        const int nq = (cch < 7) ? (cch + 1)*8 : 0;
        #pragma unroll
        for (int u = 0; u < 8; ++u) { xa[u] = w2p[(nq + u)*H2]; xb[u] = w2p[(nq + u)*H2 + 64]; }

        #pragma unroll
        for (int u = 0; u < 8; ++u) {
            const int hq = qt*64 + cch*8 + u;
            const float4 hA = *(const float4*)&hb[hq][0];
            const float4 hB = *(const float4*)&hb[hq][4];
            const float4 hC = *(const float4*)&hb[hq][8];
            const float hv[12] = {hA.x,hA.y,hA.z,hA.w, hB.x,hB.y,hB.z,hB.w, hC.x,hC.y,hC.z,hC.w};
            #pragma unroll
            for (int jj = 0; jj < 12; ++jj) {
                acc0[jj] = fmaf(hv[jj], wa[u], acc0[jj]);
                acc1[jj] = fmaf(hv[jj], wb[u], acc1[jj]);
            }
        }
        #pragma unroll
        for (int u = 0; u < 8; ++u) { wa[u] = xa[u]; wb[u] = xb[u]; }
    }
    __syncthreads();          // all hb reads done before overwrite

    // ---- partials: part[qt][c2][cc][jj] ----
    #pragma unroll
    for (int b = 0; b < 3; ++b) {
        float4 p0, p1;
        p0.x = acc0[b*4+0]; p0.y = acc0[b*4+1]; p0.z = acc0[b*4+2]; p0.w = acc0[b*4+3];
        p1.x = acc1[b*4+0]; p1.y = acc1[b*4+1]; p1.z = acc1[b*4+2]; p1.w = acc1[b*4+3];
        *(float4*)&part[qt][c2][0][b*4] = p0;
        *(float4*)&part[qt][c2][1][b*4] = p1;
    }
    __syncthreads();

    // ---- reduce quarters, layer2 bias+relu, layer3 dot over 128 c ----
    if (t < 128) {
        const int c  = t;
        const int cl = t & 63;
        const int cc = t >> 6;
        const float b2c = b2[c];
        const float w3c = W3[c];
        float v[12];
        #pragma unroll
        for (int b = 0; b < 3; ++b) {
            float4 s; s.x = 0.f; s.y = 0.f; s.z = 0.f; s.w = 0.f;
            #pragma unroll
            for (int qq = 0; qq < 4; ++qq) {
                const float4 p = *(const float4*)&part[qq][cl][cc][b*4];
                s.x += p.x; s.y += p.y; s.z += p.z; s.w += p.w;
            }
            v[b*4+0] = fmaxf(s.x + b2c, 0.f) * w3c;
            v[b*4+1] = fmaxf(s.y + b2c, 0.f) * w3c;
            v[b*4+2] = fmaxf(s.z + b2c, 0.f) * w3c;
            v[b*4+3] = fmaxf(s.w + b2c, 0.f) * w3c;
        }
        #pragma unroll
        for (int jj = 0; jj < 12; ++jj) {
            float s = v[jj];
            #pragma unroll
            for (int off = 32; off; off >>= 1) s += __shfl_down(s, off, 64);
            if ((t & 63) == 0) red[t >> 6][jj] = s;
        }
    }
    __syncthreads();
    if (t < 12) {
        const int j = j0 + t;
        const float s = red[0][t] + red[1][t] + b3[0];
        out[i*NN + j] = (i == j) ? 0.f : 1.f / (1.f + __expf(-s));
    }
}

// ---------------- Kernel C: conf [96,96,96] ----------------
// grid (96,8) = 768 blocks = exactly 3/CU. 192 threads = 4 j-groups x 48
// k-lanes; each thread 3 j x 2 k. Explicit register double-buffer: the next
// 4-h chunk's loads (4x float2 tc, 3x float4 s-broadcast, float4 V2) issue at
// the top of each chunk, consumed one chunk (144 issue-cycles) later.
#define CJT 12
#define CJG 3
__global__ __launch_bounds__(192) void conf_kernel(
    const float* __restrict__ ta, const float* __restrict__ tb,
    const float* __restrict__ tcT, const float* __restrict__ V2,
    const float* __restrict__ c2, float* __restrict__ out)
{
    const int i  = blockIdx.x;
    const int j0 = blockIdx.y * CJT;
    const int t  = threadIdx.x;         // 0..191
    const int g  = t / 48;              // j-group 0..3
    const int l  = t % 48;              // k-pair lane
    const int k0 = 2*l;                 // k = k0, k0+1

    __shared__ float sbuf[CJT][HH];     // 12 KB

    // ---- stage s[jj][h] = ta[i][h] + tb[j][h], vectorized ----
    for (int idx = t; idx < CJT*HH/4; idx += 192) {
        const int jj = idx >> 6;            // 64 float4s per row
        const int h4 = (idx & 63) << 2;
        const float4 a = *(const float4*)&ta[i*HH + h4];
        const float4 b = *(const float4*)&tb[(j0 + jj)*HH + h4];
        float4 s; s.x = a.x + b.x; s.y = a.y + b.y; s.z = a.z + b.z; s.w = a.w + b.w;
        *(float4*)&sbuf[jj][h4] = s;
    }
    __syncthreads();

    float acc[CJG][2];
    #pragma unroll
    for (int m = 0; m < CJG; ++m) { acc[m][0] = 0.f; acc[m][1] = 0.f; }

    const float* __restrict__ sb0 = &sbuf[g*CJG + 0][0];
    const float* __restrict__ sb1 = &sbuf[g*CJG + 1][0];
    const float* __restrict__ sb2 = &sbuf[g*CJG + 2][0];

#define LOADC(H0, T, VA, S)                                 \
    T[0] = *(const float2*)&tcT[((H0)+0)*NN + k0];          \
    T[1] = *(const float2*)&tcT[((H0)+1)*NN + k0];          \
    T[2] = *(const float2*)&tcT[((H0)+2)*NN + k0];          \
    T[3] = *(const float2*)&tcT[((H0)+3)*NN + k0];          \
    VA   = *(const float4*)&V2[(H0)];                       \
    S[0] = *(const float4*)&sb0[(H0)];                      \
    S[1] = *(const float4*)&sb1[(H0)];                      \
    S[2] = *(const float4*)&sb2[(H0)];

    float2 ct[4]; float4 cva; float4 cs[CJG];
    LOADC(0, ct, cva, cs);

    #pragma unroll 2
    for (int h0 = 0; h0 < HH; h0 += 4) {
        float2 nt[4]; float4 nva; float4 ns[CJG];
        const int hn = (h0 + 4) & (HH - 1);     // wraps on last iter; unused
        LOADC(hn, nt, nva, ns);

        const float vv[4] = {cva.x, cva.y, cva.z, cva.w};
        const float s[CJG][4] = {{cs[0].x,cs[0].y,cs[0].z,cs[0].w},
                                 {cs[1].x,cs[1].y,cs[1].z,cs[1].w},
                                 {cs[2].x,cs[2].y,cs[2].z,cs[2].w}};
        const float tc[4][2] = {{ct[0].x,ct[0].y},{ct[1].x,ct[1].y},
                                {ct[2].x,ct[2].y},{ct[3].x,ct[3].y}};
        #pragma unroll
        for (int u4 = 0; u4 < 4; ++u4) {
            #pragma unroll
            for (int m = 0; m < CJG; ++m) {
                acc[m][0] = fmaf(fmaxf(s[m][u4] + tc[u4][0], 0.f), vv[u4], acc[m][0]);
                acc[m][1] = fmaf(fmaxf(s[m][u4] + tc[u4][1], 0.f), vv[u4], acc[m][1]);
            }
        }
        ct[0] = nt[0]; ct[1] = nt[1]; ct[2] = nt[2]; ct[3] = nt[3];
        cva = nva;
        cs[0] = ns[0]; cs[1] = ns[1]; cs[2] = ns[2];
    }
#undef LOADC

    const float c2v = c2[0];
    #pragma unroll
    for (int m = 0; m < CJG; ++m) {
        const int j = j0 + g*CJG + m;
        float2 o;
        o.x = 1.f / (1.f + __expf(-(acc[m][0] + c2v)));
        o.y = 1.f / (1.f + __expf(-(acc[m][1] + c2v)));
        if (i == j || i == k0   || j == k0  ) o.x = 0.f;
        if (i == j || i == k0+1 || j == k0+1) o.y = 0.f;
        *(float2*)&out[(i*NN + j)*NN + k0] = o;
    }
}

extern "C" void kernel_launch(void* const* d_in, const int* in_sizes, int n_in,
                              void* d_out, int out_size, void* d_ws, size_t ws_size,
                              hipStream_t stream) {
    const float* X  = (const float*)d_in[0];
    // d_in[1] = edge_index (unused by reference)
    const float* W1 = (const float*)d_in[2];
    const float* b1 = (const float*)d_in[3];
    const float* W2 = (const float*)d_in[4];
    const float* b2 = (const float*)d_in[5];
    const float* W3 = (const float*)d_in[6];
    const float* b3 = (const float*)d_in[7];
    const float* V1 = (const float*)d_in[8];
    const float* c1 = (const float*)d_in[9];
    const float* V2 = (const float*)d_in[10];
    const float* c2 = (const float*)d_in[11];

    float* out = (float*)d_out;
    float* ws  = (float*)d_ws;
    float* pi  = ws;                 // 96*256
    float* pj  = pi + NN*HH;
    float* ta  = pj + NN*HH;
    float* tb  = ta + NN*HH;
    float* tcT = tb + NN*HH;         // 256*96

    proj_kernel<<<dim3(NN, 5), 256, 0, stream>>>(X, W1, b1, V1, c1, pi, pj, ta, tb, tcT);
    causal_kernel<<<dim3(NN, 8), 256, 0, stream>>>(pi, pj, W2, b2, W3, b3, out);
    conf_kernel<<<dim3(NN, 8), 192, 0, stream>>>(ta, tb, tcT, V2, c2, out + NN*NN);
}